// Round 1
// baseline (575.938 us; speedup 1.0000x reference)
//
#include <hip/hip_runtime.h>
#include <hip/hip_bf16.h>

// Problem: out[n,:] = concat(x[n,:], mean[batch_id[n],:]) @ W^T + b
//   N ~= 500000 nodes, IN = 128, OUT = 128, G = 1024 graphs, batch_id SORTED.
// Decomposition: out = x @ W1^T + ctx[batch_id], ctx[g] = mean[g] @ W2^T + b.
//   W1 = W[:, :128], W2 = W[:, 128:].  K of the big GEMM halves (256 -> 128).

#define G_NUM 1024
#define IN_F 128
#define OUT_F 128

typedef __attribute__((ext_vector_type(8))) short short8;   // 8 bf16 = 4 VGPRs
typedef __attribute__((ext_vector_type(4))) float f32x4;    // MFMA C/D frag

static __device__ __forceinline__ unsigned short f2bf(float f) {
    union { float f; unsigned u; } v; v.f = f;
    unsigned u = v.u;
    // round-to-nearest-even bf16
    unsigned r = (u + 0x7FFFu + ((u >> 16) & 1u)) >> 16;
    return (unsigned short)r;
}

// ---------------------------------------------------------------------------
// Kernel 1: convert W1 (= W[:, :128]) to bf16, row-major [o][k].
// ---------------------------------------------------------------------------
__global__ void k_wcvt(const float* __restrict__ W, unsigned short* __restrict__ W1b) {
    int i = blockIdx.x * 256 + threadIdx.x;     // 128*128 = 16384 elements
    if (i < OUT_F * IN_F) {
        int o = i >> 7, k = i & 127;
        W1b[i] = f2bf(W[o * 256 + k]);
    }
}

// ---------------------------------------------------------------------------
// Kernel 2: one block per graph. Binary-search segment bounds in sorted
// batch_id, accumulate fp32 segment mean, then ctx[g] = mean @ W2^T + b.
// ---------------------------------------------------------------------------
__global__ __launch_bounds__(256) void k_mean_ctx(
        const float* __restrict__ x, const int* __restrict__ bid,
        const float* __restrict__ W, const float* __restrict__ b,
        float* __restrict__ ctx, int N) {
    int g = blockIdx.x;
    int tid = threadIdx.x;

    // lower_bound(g) and lower_bound(g+1)
    int lo = 0, hi = N;
    while (lo < hi) { int m = (lo + hi) >> 1; if (bid[m] < g) lo = m + 1; else hi = m; }
    int start = lo;
    int lo2 = start, hi2 = N;
    while (lo2 < hi2) { int m = (lo2 + hi2) >> 1; if (bid[m] < g + 1) lo2 = m + 1; else hi2 = m; }
    int end = lo2;
    int cnt = end - start;

    __shared__ float4 red[8][32];
    __shared__ float ms[IN_F];

    int c4 = tid & 31;      // float4 column
    int rg = tid >> 5;      // row group 0..7
    float4 s = make_float4(0.f, 0.f, 0.f, 0.f);
    for (int r = start + rg; r < end; r += 8) {
        float4 v = *(const float4*)(x + (size_t)r * IN_F + c4 * 4);
        s.x += v.x; s.y += v.y; s.z += v.z; s.w += v.w;
    }
    red[rg][c4] = s;
    __syncthreads();
    if (tid < 32) {
        float4 t = red[0][tid];
        #pragma unroll
        for (int i = 1; i < 8; ++i) {
            float4 v = red[i][tid];
            t.x += v.x; t.y += v.y; t.z += v.z; t.w += v.w;
        }
        float inv = 1.0f / (float)(cnt > 0 ? cnt : 1);
        ms[tid * 4 + 0] = t.x * inv;
        ms[tid * 4 + 1] = t.y * inv;
        ms[tid * 4 + 2] = t.z * inv;
        ms[tid * 4 + 3] = t.w * inv;
    }
    __syncthreads();
    if (tid < OUT_F) {
        int o = tid;
        float acc = b[o];
        const float* w2 = W + o * 256 + 128;    // W2 row (L1/L2 cached)
        #pragma unroll 8
        for (int k = 0; k < IN_F; ++k) acc += ms[k] * w2[k];
        ctx[g * OUT_F + o] = acc;
    }
}

// ---------------------------------------------------------------------------
// Kernel 3: out[n][o] = sum_k x[n][k]*W1[o][k] + ctx[bid[n]][o]
// 128-row block tile, 4 waves (2x2 of 64x64), mfma_f32_16x16x32_bf16.
// B (W1 bf16) lives entirely in registers (16 frags/wave, L2-resident load).
// A tile staged fp32->bf16 into LDS, row stride 136 (uniform bank spread).
// ---------------------------------------------------------------------------
#define AS_STRIDE 136   // 128 + 8 bf16 pad -> 16B-aligned rows, even bank use

__global__ __launch_bounds__(256) void k_gemm(
        const float* __restrict__ x, const int* __restrict__ bid,
        const unsigned short* __restrict__ W1b, const float* __restrict__ ctx,
        float* __restrict__ out, int N) {
    __shared__ unsigned short As[128 * AS_STRIDE];
    __shared__ int bids[128];

    int tid = threadIdx.x;
    int row0 = blockIdx.x * 128;
    int lane = tid & 63, wave = tid >> 6;
    int l16 = lane & 15, quad = lane >> 4;
    int wrow = (wave & 1) * 64;   // wave's row offset in the 128x128 tile
    int wcol = (wave >> 1) * 64;  // wave's col offset

    // --- B fragments: B[k][n] = W1[n][k]; lane holds col n=l16, k=quad*8+j ---
    short8 bfrag[4][4];           // [kt][ot]
    #pragma unroll
    for (int ot = 0; ot < 4; ++ot) {
        int o = wcol + ot * 16 + l16;
        #pragma unroll
        for (int kt = 0; kt < 4; ++kt)
            bfrag[kt][ot] = *(const short8*)(W1b + o * IN_F + kt * 32 + quad * 8);
    }

    // --- stage x tile (fp32 -> bf16) into LDS ---
    #pragma unroll
    for (int i = 0; i < 16; ++i) {
        int r = i * 8 + (tid >> 5);          // 0..127
        int c4 = (tid & 31) * 4;             // 0..124
        int gr = row0 + r;
        float4 v = make_float4(0.f, 0.f, 0.f, 0.f);
        if (gr < N) v = *(const float4*)(x + (size_t)gr * IN_F + c4);
        ushort4 p;
        p.x = f2bf(v.x); p.y = f2bf(v.y); p.z = f2bf(v.z); p.w = f2bf(v.w);
        *(ushort4*)&As[r * AS_STRIDE + c4] = p;   // 8B-aligned
    }
    if (tid < 128) bids[tid] = (row0 + tid < N) ? bid[row0 + tid] : 0;
    __syncthreads();

    // --- MFMA: K = 128 in 4 chunks of 32 ---
    f32x4 acc[4][4];
    #pragma unroll
    for (int mt = 0; mt < 4; ++mt)
        #pragma unroll
        for (int ot = 0; ot < 4; ++ot)
            acc[mt][ot] = (f32x4){0.f, 0.f, 0.f, 0.f};

    #pragma unroll
    for (int kt = 0; kt < 4; ++kt) {
        short8 af[4];
        #pragma unroll
        for (int mt = 0; mt < 4; ++mt) {
            int m = wrow + mt * 16 + l16;    // A row; lane holds k=quad*8+j
            af[mt] = *(const short8*)&As[m * AS_STRIDE + kt * 32 + quad * 8];
        }
        #pragma unroll
        for (int mt = 0; mt < 4; ++mt)
            #pragma unroll
            for (int ot = 0; ot < 4; ++ot)
                acc[mt][ot] = __builtin_amdgcn_mfma_f32_16x16x32_bf16(
                    af[mt], bfrag[kt][ot], acc[mt][ot], 0, 0, 0);
    }

    // --- epilogue: D[row=quad*4+r][col=l16] per 16x16 tile; add ctx, store ---
    #pragma unroll
    for (int mt = 0; mt < 4; ++mt) {
        #pragma unroll
        for (int r = 0; r < 4; ++r) {
            int row = wrow + mt * 16 + quad * 4 + r;
            int grow = row0 + row;
            if (grow < N) {
                int cb = bids[row] * OUT_F;
                #pragma unroll
                for (int ot = 0; ot < 4; ++ot) {
                    int col = wcol + ot * 16 + l16;
                    out[(size_t)grow * OUT_F + col] = acc[mt][ot][r] + ctx[cb + col];
                }
            }
        }
    }
}

// ---------------------------------------------------------------------------
extern "C" void kernel_launch(void* const* d_in, const int* in_sizes, int n_in,
                              void* d_out, int out_size, void* d_ws, size_t ws_size,
                              hipStream_t stream) {
    const float* x  = (const float*)d_in[0];
    const int* bid  = (const int*)d_in[1];
    const float* W  = (const float*)d_in[2];
    const float* b  = (const float*)d_in[3];
    float* out      = (float*)d_out;
    int N = in_sizes[1];

    // workspace layout: ctx [1024*128 f32] @ 0, W1b [128*128 bf16] @ 512KB
    float* ctx = (float*)d_ws;
    unsigned short* W1b = (unsigned short*)((char*)d_ws + (size_t)G_NUM * OUT_F * sizeof(float));

    k_wcvt<<<(OUT_F * IN_F + 255) / 256, 256, 0, stream>>>(W, W1b);
    k_mean_ctx<<<G_NUM, 256, 0, stream>>>(x, bid, W, b, ctx, N);
    k_gemm<<<(N + 127) / 128, 256, 0, stream>>>(x, bid, W1b, ctx, out, N);
}

// Round 2
// 547.716 us; speedup vs baseline: 1.0515x; 1.0515x over previous
//
#include <hip/hip_runtime.h>
#include <hip/hip_bf16.h>

// Problem: out[n,:] = concat(x[n,:], mean[batch_id[n],:]) @ W^T + b
//   N ~= 500000 nodes, IN = 128, OUT = 128, G = 1024 graphs, batch_id SORTED.
// Decomposition: out = x @ W1^T + ctx[batch_id], ctx[g] = mean[g] @ W2^T + b.
//   W1 = W[:, :128], W2 = W[:, 128:].  K of the big GEMM halves (256 -> 128).

#define G_NUM 1024
#define IN_F 128
#define OUT_F 128

typedef __attribute__((ext_vector_type(8))) short short8;   // 8 bf16 = 4 VGPRs
typedef __attribute__((ext_vector_type(4))) float f32x4;    // MFMA C/D frag

static __device__ __forceinline__ unsigned short f2bf(float f) {
    union { float f; unsigned u; } v; v.f = f;
    unsigned u = v.u;
    unsigned r = (u + 0x7FFFu + ((u >> 16) & 1u)) >> 16;    // RNE
    return (unsigned short)r;
}

static __device__ __forceinline__ short8 pack8(float4 a, float4 b) {
    short8 o;
    o[0] = (short)f2bf(a.x); o[1] = (short)f2bf(a.y);
    o[2] = (short)f2bf(a.z); o[3] = (short)f2bf(a.w);
    o[4] = (short)f2bf(b.x); o[5] = (short)f2bf(b.y);
    o[6] = (short)f2bf(b.z); o[7] = (short)f2bf(b.w);
    return o;
}

// ---------------------------------------------------------------------------
// Kernel 1: convert W1 (= W[:, :128]) to bf16, row-major [o][k].
// ---------------------------------------------------------------------------
__global__ void k_wcvt(const float* __restrict__ W, unsigned short* __restrict__ W1b) {
    int i = blockIdx.x * 256 + threadIdx.x;     // 128*128 = 16384 elements
    if (i < OUT_F * IN_F) {
        int o = i >> 7, k = i & 127;
        W1b[i] = f2bf(W[o * 256 + k]);
    }
}

// ---------------------------------------------------------------------------
// Kernel 2: one block per graph. Binary-search segment bounds in sorted
// batch_id; 4-way unrolled fp32 accumulation (4 independent 1KB loads in
// flight per wave); then ctx[g] = mean @ W2^T + b.
// ---------------------------------------------------------------------------
__global__ __launch_bounds__(256) void k_mean_ctx(
        const float* __restrict__ x, const int* __restrict__ bid,
        const float* __restrict__ W, const float* __restrict__ b,
        float* __restrict__ ctx, int N) {
    int g = blockIdx.x;
    int tid = threadIdx.x;

    int lo = 0, hi = N;
    while (lo < hi) { int m = (lo + hi) >> 1; if (bid[m] < g) lo = m + 1; else hi = m; }
    int start = lo;
    int lo2 = start, hi2 = N;
    while (lo2 < hi2) { int m = (lo2 + hi2) >> 1; if (bid[m] < g + 1) lo2 = m + 1; else hi2 = m; }
    int end = lo2;
    int cnt = end - start;

    __shared__ float4 red[8][32];
    __shared__ float ms[IN_F];

    int c4 = tid & 31;      // float4 column
    int rg = tid >> 5;      // row stripe 0..7
    float4 s0 = make_float4(0.f, 0.f, 0.f, 0.f);
    float4 s1 = s0, s2 = s0, s3 = s0;

    int r = start + rg;
    for (; r + 24 < end; r += 32) {
        float4 a = *(const float4*)(x + (size_t)(r     ) * IN_F + c4 * 4);
        float4 c = *(const float4*)(x + (size_t)(r +  8) * IN_F + c4 * 4);
        float4 d = *(const float4*)(x + (size_t)(r + 16) * IN_F + c4 * 4);
        float4 e = *(const float4*)(x + (size_t)(r + 24) * IN_F + c4 * 4);
        s0.x += a.x; s0.y += a.y; s0.z += a.z; s0.w += a.w;
        s1.x += c.x; s1.y += c.y; s1.z += c.z; s1.w += c.w;
        s2.x += d.x; s2.y += d.y; s2.z += d.z; s2.w += d.w;
        s3.x += e.x; s3.y += e.y; s3.z += e.z; s3.w += e.w;
    }
    for (; r < end; r += 8) {
        float4 a = *(const float4*)(x + (size_t)r * IN_F + c4 * 4);
        s0.x += a.x; s0.y += a.y; s0.z += a.z; s0.w += a.w;
    }
    s0.x += s1.x + s2.x + s3.x;
    s0.y += s1.y + s2.y + s3.y;
    s0.z += s1.z + s2.z + s3.z;
    s0.w += s1.w + s2.w + s3.w;

    red[rg][c4] = s0;
    __syncthreads();
    if (tid < 32) {
        float4 t = red[0][tid];
        #pragma unroll
        for (int i = 1; i < 8; ++i) {
            float4 v = red[i][tid];
            t.x += v.x; t.y += v.y; t.z += v.z; t.w += v.w;
        }
        float inv = 1.0f / (float)(cnt > 0 ? cnt : 1);
        ms[tid * 4 + 0] = t.x * inv;
        ms[tid * 4 + 1] = t.y * inv;
        ms[tid * 4 + 2] = t.z * inv;
        ms[tid * 4 + 3] = t.w * inv;
    }
    __syncthreads();
    if (tid < OUT_F) {
        int o = tid;
        float acc = b[o];
        const float* w2 = W + o * 256 + 128;    // W2 row (L2 cached)
        #pragma unroll 8
        for (int k = 0; k < IN_F; ++k) acc += ms[k] * w2[k];
        ctx[g * OUT_F + o] = acc;
    }
}

// ---------------------------------------------------------------------------
// Kernel 3: out[n][o] = sum_k x[n][k]*W1[o][k] + ctx[bid[n]][o]
// LDS-free, barrier-free. 128-row block tile, 4 waves (2x2 of 64x64),
// mfma_f32_16x16x32_bf16. A loaded global->reg (fp32), converted to bf16
// in-register. B (bf16 W1) loaded per-kt from L2. Fully unrolled -> ~40
// independent loads in flight per wave.
// ---------------------------------------------------------------------------
__global__ __launch_bounds__(256, 2) void k_gemm(
        const float* __restrict__ x, const int* __restrict__ bid,
        const unsigned short* __restrict__ W1b, const float* __restrict__ ctx,
        float* __restrict__ out, int N) {
    int tid = threadIdx.x;
    int row0 = blockIdx.x * 128;
    int lane = tid & 63, wave = tid >> 6;
    int l16 = lane & 15, quad = lane >> 4;
    int wrow = (wave & 1) * 64;   // wave's row offset in the 128-row tile
    int wcol = (wave >> 1) * 64;  // wave's col offset

    f32x4 acc[4][4];
    #pragma unroll
    for (int mt = 0; mt < 4; ++mt)
        #pragma unroll
        for (int ot = 0; ot < 4; ++ot)
            acc[mt][ot] = (f32x4){0.f, 0.f, 0.f, 0.f};

    #pragma unroll
    for (int kt = 0; kt < 4; ++kt) {
        // B frags for this kt: lane holds col n=l16, k=quad*8+j
        short8 bf[4];
        #pragma unroll
        for (int ot = 0; ot < 4; ++ot)
            bf[ot] = *(const short8*)(W1b + (wcol + ot * 16 + l16) * IN_F + kt * 32 + quad * 8);
        // A frags: lane holds row m=l16 (within 16-tile), k=quad*8+j
        short8 af[4];
        #pragma unroll
        for (int mt = 0; mt < 4; ++mt) {
            int r = row0 + wrow + mt * 16 + l16;
            float4 v0 = make_float4(0.f, 0.f, 0.f, 0.f), v1 = v0;
            if (r < N) {
                const float* p = x + (size_t)r * IN_F + kt * 32 + quad * 8;
                v0 = *(const float4*)p;
                v1 = *(const float4*)(p + 4);
            }
            af[mt] = pack8(v0, v1);
        }
        #pragma unroll
        for (int mt = 0; mt < 4; ++mt)
            #pragma unroll
            for (int ot = 0; ot < 4; ++ot)
                acc[mt][ot] = __builtin_amdgcn_mfma_f32_16x16x32_bf16(
                    af[mt], bf[ot], acc[mt][ot], 0, 0, 0);
    }

    // --- epilogue: D[row=quad*4+r][col=l16] per 16x16 tile ---
    int lastrow = row0 + 127 < N ? row0 + 127 : N - 1;
    int b_lo = bid[row0], b_hi = bid[lastrow];
    if (b_lo == b_hi) {
        // whole tile in one graph (~74% of tiles): one ctx row, 4 loads/lane
        float cv[4];
        #pragma unroll
        for (int ot = 0; ot < 4; ++ot)
            cv[ot] = ctx[b_lo * OUT_F + wcol + ot * 16 + l16];
        #pragma unroll
        for (int mt = 0; mt < 4; ++mt) {
            #pragma unroll
            for (int r4 = 0; r4 < 4; ++r4) {
                int row = row0 + wrow + mt * 16 + quad * 4 + r4;
                if (row < N) {
                    #pragma unroll
                    for (int ot = 0; ot < 4; ++ot)
                        out[(size_t)row * OUT_F + wcol + ot * 16 + l16] =
                            acc[mt][ot][r4] + cv[ot];
                }
            }
        }
    } else {
        #pragma unroll
        for (int mt = 0; mt < 4; ++mt) {
            #pragma unroll
            for (int r4 = 0; r4 < 4; ++r4) {
                int row = row0 + wrow + mt * 16 + quad * 4 + r4;
                if (row < N) {
                    int cb = bid[row] * OUT_F;
                    #pragma unroll
                    for (int ot = 0; ot < 4; ++ot)
                        out[(size_t)row * OUT_F + wcol + ot * 16 + l16] =
                            acc[mt][ot][r4] + ctx[cb + wcol + ot * 16 + l16];
                }
            }
        }
    }
}

// ---------------------------------------------------------------------------
extern "C" void kernel_launch(void* const* d_in, const int* in_sizes, int n_in,
                              void* d_out, int out_size, void* d_ws, size_t ws_size,
                              hipStream_t stream) {
    const float* x  = (const float*)d_in[0];
    const int* bid  = (const int*)d_in[1];
    const float* W  = (const float*)d_in[2];
    const float* b  = (const float*)d_in[3];
    float* out      = (float*)d_out;
    int N = in_sizes[1];

    // workspace layout: ctx [1024*128 f32] @ 0, W1b [128*128 bf16] after
    float* ctx = (float*)d_ws;
    unsigned short* W1b = (unsigned short*)((char*)d_ws + (size_t)G_NUM * OUT_F * sizeof(float));

    k_wcvt<<<(OUT_F * IN_F + 255) / 256, 256, 0, stream>>>(W, W1b);
    k_mean_ctx<<<G_NUM, 256, 0, stream>>>(x, bid, W, b, ctx, N);
    k_gemm<<<(N + 127) / 128, 256, 0, stream>>>(x, bid, W1b, ctx, out, N);
}